// Round 7
// baseline (299.958 us; speedup 1.0000x reference)
//
#include <hip/hip_runtime.h>
#include <hip/hip_bf16.h>
#include <stdint.h>

#define EPS_BN 1e-5f

constexpr int Fn = 32;    // frames
constexpr int Pn = 64;    // peds per frame
constexpr int Bn = 2048;  // batch
constexpr int Hn = 128;   // h_dim
constexpr int En = 64;    // embed dim
constexpr int Mn = 512;   // GEMM K
constexpr int Dn = 1024;  // GEMM N

using bf16x8  = __attribute__((ext_vector_type(8))) short;
using f32x16  = __attribute__((ext_vector_type(16))) float;

static __device__ __forceinline__ float    bcf(uint32_t u) { return __builtin_bit_cast(float, u); }
static __device__ __forceinline__ uint32_t bcu(float f)    { return __builtin_bit_cast(uint32_t, f); }
static __device__ __forceinline__ unsigned short bfbits(float f) {
  return __builtin_bit_cast(unsigned short, __float2bfloat16(f));
}

// async 16B/lane global -> LDS (LDS base wave-uniform; HW adds lane*16)
static __device__ __forceinline__ void dma16(const uint4* g, const uint4* l) {
  __builtin_amdgcn_global_load_lds(
      (const __attribute__((address_space(1))) unsigned int*)g,
      (__attribute__((address_space(3))) unsigned int*)l, 16, 0, 0);
}

// r0/r1 = bf16 max(a0,q), max(a1,q): packed-pair max with shared q-shift.
// hi halves compared as fp32 with garbage low mantissa bits: if top16 differ,
// fp32 compare agrees with bf16 compare; if equal, either pick gives same top16.
static __device__ __forceinline__ void mk2(uint4 a0, uint4 a1, uint4 q,
                                           bf16x8& r0, bf16x8& r1) {
  uint4 x0, x1;
#pragma unroll
  for (int v = 0; v < 4; ++v) {
    uint32_t qw  = ((const uint32_t*)&q)[v];
    uint32_t a0w = ((const uint32_t*)&a0)[v], a1w = ((const uint32_t*)&a1)[v];
    float qlo = bcf(qw << 16);
    float m0lo = fmaxf(bcf(a0w << 16), qlo);
    float m1lo = fmaxf(bcf(a1w << 16), qlo);
    float m0hi = fmaxf(bcf(a0w), bcf(qw));
    float m1hi = fmaxf(bcf(a1w), bcf(qw));
    ((uint32_t*)&x0)[v] = __builtin_amdgcn_perm(bcu(m0hi), bcu(m0lo), 0x07060302u);
    ((uint32_t*)&x1)[v] = __builtin_amdgcn_perm(bcu(m1hi), bcu(m1lo), 0x07060302u);
  }
  r0 = __builtin_bit_cast(bf16x8, x0);
  r1 = __builtin_bit_cast(bf16x8, x1);
}

// ---------------------------------------------------------------------------
// prep_all: 257 blocks x 512 threads.
//  [0,128):   Agb/Qgb bf16 (16 batch rows/block), BN1+embedding folded.
//  [128,256): W2g in 32x32x16 MFMA B-fragment granule order (s2 folded).
//  256:       G0/G1 (= (Wr .* s1) @ W2s, 2x1024) and c2.
// ---------------------------------------------------------------------------
__global__ void prep_all(const float* __restrict__ hs, const float* __restrict__ pos,
                         const float* __restrict__ We, const float* __restrict__ be,
                         const float* __restrict__ W1, const float* __restrict__ b1,
                         const float* __restrict__ g1, const float* __restrict__ beta1,
                         const float* __restrict__ rm1, const float* __restrict__ rv1,
                         const float* __restrict__ W2, const float* __restrict__ b2,
                         const float* __restrict__ g2, const float* __restrict__ beta2,
                         const float* __restrict__ rm2, const float* __restrict__ rv2,
                         __hip_bfloat16* __restrict__ Agb, __hip_bfloat16* __restrict__ Qgb,
                         uint4* __restrict__ W2g, float* __restrict__ G0,
                         float* __restrict__ G1, float* __restrict__ c2) {
  __shared__ float smem[64 * 65];
  int bid = blockIdx.x, t = threadIdx.x;
  if (bid < 128) {
    // ---- Ag/Qg for 16 batch rows ----
    int rb = bid * 16, m = t;
    float* hsh = smem;          // 16*128 = 2048 floats
    float* psh = smem + 2048;   // 32 floats
#pragma unroll
    for (int r4 = 0; r4 < 4; ++r4) hsh[r4 * 512 + t] = hs[rb * Hn + r4 * 512 + t];
    if (t < 32) psh[t] = pos[rb * 2 + t];
    __syncthreads();
    float w0 = 0.f, w1 = 0.f, c = 0.f;
    for (int e = 0; e < En; ++e) {
      float w = W1[e * Mn + m];
      w0 += We[e] * w; w1 += We[En + e] * w; c += be[e] * w;
    }
    c += b1[m];
    float s  = g1[m] * rsqrtf(rv1[m] + EPS_BN);
    float tt = beta1[m] - rm1[m] * s;
    float acc[16];
#pragma unroll
    for (int ri = 0; ri < 16; ++ri) acc[ri] = c;
    for (int e = 0; e < Hn; ++e) {
      float w = W1[(En + e) * Mn + m];
#pragma unroll
      for (int ri = 0; ri < 16; ++ri) acc[ri] += hsh[ri * Hn + e] * w;
    }
#pragma unroll
    for (int ri = 0; ri < 16; ++ri) {
      float q = psh[ri * 2] * w0 + psh[ri * 2 + 1] * w1;
      Agb[(rb + ri) * Mn + m] = __float2bfloat16((acc[ri] + q) * s + tt);
      Qgb[(rb + ri) * Mn + m] = __float2bfloat16(q * s);
    }
  } else if (bid < 256) {
    // ---- W2 -> 32-col B-fragment granules (s2 folded) ----
    int b2i = bid - 128;                 // 0..127
    int d0 = (b2i & 15) * 64, k0 = (b2i >> 4) * 64;
    int col = t & 63, row8 = t >> 6;
#pragma unroll
    for (int rr = 0; rr < 8; ++rr) {
      int row = rr * 8 + row8;
      smem[row * 65 + col] = W2[(k0 + row) * Dn + d0 + col];  // [k_local][d_local]
    }
    __syncthreads();
    int lane = t & 63, q8 = t >> 6;
    int sel_n = q8 & 1, sel_ks = q8 >> 1;
    int dl = sel_n * 32 + (lane & 31), d = d0 + dl;
    float sf = g2[d] * rsqrtf(rv2[d] + EPS_BN);
    int kb = sel_ks * 16 + (lane >> 5) * 8;
    uint32_t wd[4];
#pragma unroll
    for (int h = 0; h < 4; ++h) {
      uint32_t u0 = bfbits(smem[(kb + 2 * h) * 65 + dl] * sf);
      uint32_t u1 = bfbits(smem[(kb + 2 * h + 1) * 65 + dl] * sf);
      wd[h] = u0 | (u1 << 16);
    }
    int n32 = (d0 >> 5) + sel_n;
    int ks  = (k0 >> 4) + sel_ks;
    W2g[(n32 * 32 + ks) * 64 + (t & 63)] = (uint4){wd[0], wd[1], wd[2], wd[3]};
  } else {
    // ---- G = (Wr .* s1) @ (W2 .* s2) : 2 x 1024 ; and c2 ----
    float* wr0 = smem;        // 512
    float* wr1 = smem + 512;  // 512
    {
      int m = t;  // 512 threads
      float w0 = 0.f, w1 = 0.f;
      for (int e = 0; e < En; ++e) {
        float w = W1[e * Mn + m];
        w0 += We[e] * w; w1 += We[En + e] * w;
      }
      float s = g1[m] * rsqrtf(rv1[m] + EPS_BN);
      wr0[m] = w0 * s; wr1[m] = w1 * s;
    }
    __syncthreads();
    float a0 = 0.f, a1 = 0.f, d0 = 0.f, d1 = 0.f;
#pragma unroll 4
    for (int m = 0; m < Mn; ++m) {
      float wA = W2[m * Dn + t];
      float wB = W2[m * Dn + t + 512];
      a0 += wr0[m] * wA; a1 += wr1[m] * wA;
      d0 += wr0[m] * wB; d1 += wr1[m] * wB;
    }
#pragma unroll
    for (int h = 0; h < 2; ++h) {
      int dd = t + h * 512;
      float g0v = h ? d0 : a0, g1v = h ? d1 : a1;
      float s2v = g2[dd] * rsqrtf(rv2[dd] + EPS_BN);
      G0[dd] = g0v * s2v;
      G1[dd] = g1v * s2v;
      c2[dd] = b2[dd] * s2v + beta2[dd] - rm2[dd] * s2v;
    }
  }
}

// ---------------------------------------------------------------------------
// gemm_pool: 32x32x16 MFMA. Block = 4 i x 64 j x 128 d; wave = one i, all j.
//  A-operand = max(Ag[j,k], Qg[i,k]) (bf16-exact); subtraction of Qg@W2s done
//  in the epilogue via R[i,d] = pos_i . G[:,d] (bilinear pull-out).
//  Staging: phase = 2 kc. A (2x8KB) and B (2x16KB) double-buffered in 48KB
//  LDS; phase p+1 DMA issued right after phase p's barrier -> each barrier's
//  vmcnt drain is ~free (full phase of slack). 8 barriers total.
//  Inner loop register-double-buffers the 6 operand ds_reads one kstep ahead.
// ---------------------------------------------------------------------------
__launch_bounds__(256, 2)
__global__ void gemm_pool(const __hip_bfloat16* __restrict__ Agb,
                          const __hip_bfloat16* __restrict__ Qgb,
                          const uint4* __restrict__ W2g,
                          const float* __restrict__ pos,
                          const float* __restrict__ G0, const float* __restrict__ G1,
                          const float* __restrict__ c2, float* __restrict__ out) {
  __shared__ uint4 SH[3072];  // A: [0,1024) 2x8KB; B: [1024,3072) 2x16KB

  int ct = blockIdx.x;   // 0..7   d-128 tile
  int rt = blockIdx.y;   // 0..511 (frame, i-quad)
  int f = rt >> 4, i0 = (rt & 15) * 4;

  int t = threadIdx.x, lane = t & 63, w = t >> 6;
  int i = i0 + w;

  const uint4* aGL = (const uint4*)(Agb + (size_t)f * Pn * Mn) +
                     (size_t)(lane & 31) * 64 + (lane >> 5);
  const uint4* bGL = W2g + (size_t)(4 * ct) * 32 * 64 + lane;
  const uint4* qP  = (const uint4*)(Qgb + (size_t)(f * Pn + i) * Mn) + (lane >> 5);
  float px = pos[(f * Pn + i) * 2], py = pos[(f * Pn + i) * 2 + 1];

  // issue the 24 DMA slots of phase p (A 8KB + B 16KB) into buffer p&1
  auto stage = [&](int p) {
    int buf = p & 1;
#pragma unroll
    for (int s6 = 0; s6 < 6; ++s6) {
      int s = w * 6 + s6;  // 0..23
      if (s < 8) {         // A slot: kcl=s>>2, kst=(s>>1)&1, jf=s&1
        int kcl = s >> 2, kst = (s >> 1) & 1, jf = s & 1;
        dma16(aGL + (size_t)jf * 2048 + (p * 2 + kcl) * 4 + kst * 2,
              SH + buf * 512 + s * 64);
      } else {             // B slot: kq=sb>>2, nf=sb&3 ; global ks = p*4+kq
        int sb = s - 8, kq = sb >> 2, nf = sb & 3;
        dma16(bGL + (nf * 32 + p * 4 + kq) * 64,
              SH + 1024 + buf * 1024 + sb * 64);
      }
    }
  };

  f32x16 acc[2][4];  // [jf][nf]
#pragma unroll
  for (int jf = 0; jf < 2; ++jf)
#pragma unroll
    for (int nf = 0; nf < 4; ++nf)
      acc[jf][nf] = (f32x16){0.f,0.f,0.f,0.f,0.f,0.f,0.f,0.f,
                             0.f,0.f,0.f,0.f,0.f,0.f,0.f,0.f};

  stage(0);
  uint4 qc0 = qP[0], qc1 = qP[2];  // kc=0 Q fragments
  uint4 qn0, qn1;

#pragma unroll
  for (int p = 0; p < 8; ++p) {
    __syncthreads();               // buffer p ready (DMA issued a phase ago)
    if (p < 7) stage(p + 1);       // overlap next phase's DMA with compute
    int abase = (p & 1) * 512 + lane;
    int bbase = 1024 + (p & 1) * 1024 + lane;

    // preload kstep-0 operands
    uint4 cA0 = SH[abase], cA1 = SH[abase + 64];
    uint4 cB[4];
#pragma unroll
    for (int nf = 0; nf < 4; ++nf) cB[nf] = SH[bbase + nf * 64];

#pragma unroll
    for (int ks = 0; ks < 4; ++ks) {
      // register prefetch of kstep ks+1 (same buffer)
      uint4 nA0, nA1, nB[4];
      if (ks < 3) {
        nA0 = SH[abase + (ks + 1) * 128];
        nA1 = SH[abase + (ks + 1) * 128 + 64];
#pragma unroll
        for (int nf = 0; nf < 4; ++nf) nB[nf] = SH[bbase + ((ks + 1) * 4 + nf) * 64];
      }
      // Q prefetch (2-kstep distance)
      if (ks == 0) { qn0 = qP[(p * 2 + 1) * 4]; qn1 = qP[(p * 2 + 1) * 4 + 2]; }
      if (ks == 2) {
        int knc = (p < 7) ? p * 2 + 2 : 15;
        qn0 = qP[knc * 4]; qn1 = qP[knc * 4 + 2];
      }

      bf16x8 af0, af1;
      mk2(cA0, cA1, (ks & 1) ? qc1 : qc0, af0, af1);
#pragma unroll
      for (int nf = 0; nf < 4; ++nf) {
        bf16x8 bg = __builtin_bit_cast(bf16x8, cB[nf]);
        acc[0][nf] = __builtin_amdgcn_mfma_f32_32x32x16_bf16(af0, bg, acc[0][nf], 0, 0, 0);
        acc[1][nf] = __builtin_amdgcn_mfma_f32_32x32x16_bf16(af1, bg, acc[1][nf], 0, 0, 0);
      }
      if (ks & 1) { qc0 = qn0; qc1 = qn1; }
      if (ks < 3) {
        cA0 = nA0; cA1 = nA1;
#pragma unroll
        for (int nf = 0; nf < 4; ++nf) cB[nf] = nB[nf];
      }
    }
  }

  // ---- epilogue (in-wave): S_max over 64 j, then relu(S - R + c2) ----
  // C layout (32x32): col=lane&31, row=(reg&3)+8*(reg>>2)+4*(lane>>5).
#pragma unroll
  for (int nf = 0; nf < 4; ++nf) {
    float mx = -3.0e38f;
#pragma unroll
    for (int jf = 0; jf < 2; ++jf)
#pragma unroll
      for (int rg = 0; rg < 16; ++rg)
        mx = fmaxf(mx, acc[jf][nf][rg]);
    mx = fmaxf(mx, __shfl_xor(mx, 32));
    if (lane < 32) {
      int d = ct * 128 + nf * 32 + (lane & 31);
      float r = px * G0[d] + py * G1[d];
      out[(f * Pn + i) * Dn + d] = fmaxf(mx - r + c2[d], 0.f);
    }
  }
}

// ---------------------------------------------------------------------------
extern "C" void kernel_launch(void* const* d_in, const int* in_sizes, int n_in,
                              void* d_out, int out_size, void* d_ws, size_t ws_size,
                              hipStream_t stream) {
  const float* hs    = (const float*)d_in[0];
  const float* pos   = (const float*)d_in[1];
  // d_in[2] seq_start_end: unused (equal-size frames, P=64)
  const float* We    = (const float*)d_in[3];
  const float* be    = (const float*)d_in[4];
  const float* W1    = (const float*)d_in[5];
  const float* b1    = (const float*)d_in[6];
  const float* g1    = (const float*)d_in[7];
  const float* beta1 = (const float*)d_in[8];
  const float* W2    = (const float*)d_in[9];
  const float* b2    = (const float*)d_in[10];
  const float* g2    = (const float*)d_in[11];
  const float* beta2 = (const float*)d_in[12];
  const float* rm1   = (const float*)d_in[13];
  const float* rv1   = (const float*)d_in[14];
  const float* rm2   = (const float*)d_in[15];
  const float* rv2   = (const float*)d_in[16];

  char* ws = (char*)d_ws;
  // layout: c2 4KB | G0 4KB | G1 4KB | Agb 2MB | Qgb 2MB | W2g 1MB
  float* c2 = (float*)(ws + 0);
  float* G0 = (float*)(ws + 4096);
  float* G1 = (float*)(ws + 8192);
  __hip_bfloat16* Agb = (__hip_bfloat16*)(ws + 12288);
  __hip_bfloat16* Qgb = (__hip_bfloat16*)(ws + 12288 + 2097152);
  uint4* W2g = (uint4*)(ws + 12288 + 2 * 2097152);
  float* out = (float*)d_out;

  prep_all<<<257, 512, 0, stream>>>(hs, pos, We, be, W1, b1, g1, beta1, rm1, rv1,
                                    W2, b2, g2, beta2, rm2, rv2, Agb, Qgb, W2g,
                                    G0, G1, c2);
  gemm_pool<<<dim3(Dn / 128, (Fn * Pn * Pn) / 256), 256, 0, stream>>>(
      Agb, Qgb, W2g, pos, G0, G1, c2, out);
}

// Round 8
// 264.665 us; speedup vs baseline: 1.1333x; 1.1333x over previous
//
#include <hip/hip_runtime.h>
#include <hip/hip_bf16.h>
#include <stdint.h>

#define EPS_BN 1e-5f

constexpr int Fn = 32;    // frames
constexpr int Pn = 64;    // peds per frame
constexpr int Bn = 2048;  // batch
constexpr int Hn = 128;   // h_dim
constexpr int En = 64;    // embed dim
constexpr int Mn = 512;   // GEMM K
constexpr int Dn = 1024;  // GEMM N

using bf16x8  = __attribute__((ext_vector_type(8))) short;
using f32x16  = __attribute__((ext_vector_type(16))) float;

static __device__ __forceinline__ float    bcf(uint32_t u) { return __builtin_bit_cast(float, u); }
static __device__ __forceinline__ uint32_t bcu(float f)    { return __builtin_bit_cast(uint32_t, f); }
static __device__ __forceinline__ unsigned short bfbits(float f) {
  return __builtin_bit_cast(unsigned short, __float2bfloat16(f));
}

// async 16B/lane global -> LDS (LDS base wave-uniform; HW adds lane*16)
static __device__ __forceinline__ void dma16(const uint4* g, const uint4* l) {
  __builtin_amdgcn_global_load_lds(
      (const __attribute__((address_space(1))) unsigned int*)g,
      (__attribute__((address_space(3))) unsigned int*)l, 16, 0, 0);
}

// r0/r1 = bf16 max(a0,q), max(a1,q): packed-pair max with shared q-shift.
// (hi halves compared as fp32 with garbage low mantissa: picks same top16)
static __device__ __forceinline__ void mk2(uint4 a0, uint4 a1, uint4 q,
                                           bf16x8& r0, bf16x8& r1) {
  uint4 x0, x1;
#pragma unroll
  for (int v = 0; v < 4; ++v) {
    uint32_t qw  = ((const uint32_t*)&q)[v];
    uint32_t a0w = ((const uint32_t*)&a0)[v], a1w = ((const uint32_t*)&a1)[v];
    float qlo = bcf(qw << 16);
    float m0lo = fmaxf(bcf(a0w << 16), qlo);
    float m1lo = fmaxf(bcf(a1w << 16), qlo);
    float m0hi = fmaxf(bcf(a0w), bcf(qw));
    float m1hi = fmaxf(bcf(a1w), bcf(qw));
    ((uint32_t*)&x0)[v] = __builtin_amdgcn_perm(bcu(m0hi), bcu(m0lo), 0x07060302u);
    ((uint32_t*)&x1)[v] = __builtin_amdgcn_perm(bcu(m1hi), bcu(m1lo), 0x07060302u);
  }
  r0 = __builtin_bit_cast(bf16x8, x0);
  r1 = __builtin_bit_cast(bf16x8, x1);
}

// ---------------------------------------------------------------------------
// prep_all: 272 blocks x 512 threads.
//  [0,128):   Agb/Qgb bf16 (16 batch rows/block), BN1+embedding folded.
//  [128,256): W2g in 32x32x16 MFMA B-fragment granule order (s2 folded).
//  [256,272): G0/G1 (= (Wr .* s1) @ W2s, 2x1024, 64 d-cols/block) + c2.
// ---------------------------------------------------------------------------
__global__ void prep_all(const float* __restrict__ hs, const float* __restrict__ pos,
                         const float* __restrict__ We, const float* __restrict__ be,
                         const float* __restrict__ W1, const float* __restrict__ b1,
                         const float* __restrict__ g1, const float* __restrict__ beta1,
                         const float* __restrict__ rm1, const float* __restrict__ rv1,
                         const float* __restrict__ W2, const float* __restrict__ b2,
                         const float* __restrict__ g2, const float* __restrict__ beta2,
                         const float* __restrict__ rm2, const float* __restrict__ rv2,
                         __hip_bfloat16* __restrict__ Agb, __hip_bfloat16* __restrict__ Qgb,
                         uint4* __restrict__ W2g, float* __restrict__ G0,
                         float* __restrict__ G1, float* __restrict__ c2) {
  __shared__ float smem[64 * 65];
  int bid = blockIdx.x, t = threadIdx.x;
  if (bid < 128) {
    // ---- Ag/Qg for 16 batch rows ----
    int rb = bid * 16, m = t;
    float* hsh = smem;          // 2048 floats
    float* psh = smem + 2048;   // 32 floats
#pragma unroll
    for (int r4 = 0; r4 < 4; ++r4) hsh[r4 * 512 + t] = hs[rb * Hn + r4 * 512 + t];
    if (t < 32) psh[t] = pos[rb * 2 + t];
    __syncthreads();
    float w0 = 0.f, w1 = 0.f, c = 0.f;
    for (int e = 0; e < En; ++e) {
      float w = W1[e * Mn + m];
      w0 += We[e] * w; w1 += We[En + e] * w; c += be[e] * w;
    }
    c += b1[m];
    float s  = g1[m] * rsqrtf(rv1[m] + EPS_BN);
    float tt = beta1[m] - rm1[m] * s;
    float acc[16];
#pragma unroll
    for (int ri = 0; ri < 16; ++ri) acc[ri] = c;
    for (int e = 0; e < Hn; ++e) {
      float w = W1[(En + e) * Mn + m];
#pragma unroll
      for (int ri = 0; ri < 16; ++ri) acc[ri] += hsh[ri * Hn + e] * w;
    }
#pragma unroll
    for (int ri = 0; ri < 16; ++ri) {
      float q = psh[ri * 2] * w0 + psh[ri * 2 + 1] * w1;
      Agb[(rb + ri) * Mn + m] = __float2bfloat16((acc[ri] + q) * s + tt);
      Qgb[(rb + ri) * Mn + m] = __float2bfloat16(q * s);
    }
  } else if (bid < 256) {
    // ---- W2 -> 32-col B-fragment granules (s2 folded) ----
    int b2i = bid - 128;                 // 0..127
    int d0 = (b2i & 15) * 64, k0 = (b2i >> 4) * 64;
    int col = t & 63, row8 = t >> 6;
#pragma unroll
    for (int rr = 0; rr < 8; ++rr) {
      int row = rr * 8 + row8;
      smem[row * 65 + col] = W2[(k0 + row) * Dn + d0 + col];  // [k_local][d_local]
    }
    __syncthreads();
    int lane = t & 63, q8 = t >> 6;
    int sel_n = q8 & 1, sel_ks = q8 >> 1;
    int dl = sel_n * 32 + (lane & 31), d = d0 + dl;
    float sf = g2[d] * rsqrtf(rv2[d] + EPS_BN);
    int kb = sel_ks * 16 + (lane >> 5) * 8;
    uint32_t wd[4];
#pragma unroll
    for (int h = 0; h < 4; ++h) {
      uint32_t u0 = bfbits(smem[(kb + 2 * h) * 65 + dl] * sf);
      uint32_t u1 = bfbits(smem[(kb + 2 * h + 1) * 65 + dl] * sf);
      wd[h] = u0 | (u1 << 16);
    }
    int n32 = (d0 >> 5) + sel_n;
    int ks  = (k0 >> 4) + sel_ks;
    W2g[(n32 * 32 + ks) * 64 + lane] = (uint4){wd[0], wd[1], wd[2], wd[3]};
  } else {
    // ---- G slice (64 d-cols) + c2 ----
    int gb = bid - 256;           // 0..15
    int d0g = gb * 64;
    float* wr0 = smem;            // [0,512)
    float* wr1 = smem + 512;      // [512,1024)
    {
      int m = t;
      float w0 = 0.f, w1 = 0.f;
      for (int e = 0; e < En; ++e) {
        float w = W1[e * Mn + m];
        w0 += We[e] * w; w1 += We[En + e] * w;
      }
      float s = g1[m] * rsqrtf(rv1[m] + EPS_BN);
      wr0[m] = w0 * s; wr1[m] = w1 * s;
    }
    __syncthreads();
    int dl = t & 63, part = t >> 6;   // 8 m-parts x 64 d
    float p0 = 0.f, p1 = 0.f;
#pragma unroll 4
    for (int mm = 0; mm < 64; ++mm) {
      int m = part * 64 + mm;
      float wv = W2[m * Dn + d0g + dl];
      p0 += wr0[m] * wv; p1 += wr1[m] * wv;
    }
    float* pr = smem + 1024;
    pr[part * 64 + dl] = p0;
    pr[512 + part * 64 + dl] = p1;
    __syncthreads();
    if (t < 128) {
      int which = t >> 6, dd = d0g + (t & 63);
      float s2v = g2[dd] * rsqrtf(rv2[dd] + EPS_BN);
      float sum = 0.f;
#pragma unroll
      for (int pp = 0; pp < 8; ++pp) sum += pr[which * 512 + pp * 64 + (t & 63)];
      (which ? G1 : G0)[dd] = sum * s2v;
      if (which == 0) c2[dd] = b2[dd] * s2v + beta2[dd] - rm2[dd] * s2v;
    }
  }
}

// ---------------------------------------------------------------------------
// gemm_pool: 32x32x16 MFMA. Block = 8 i x 64 j x 128 d, ONE block/CU,
// 1 wave/SIMD (__launch_bounds__(256,1): ~512 regs/wave available).
// Wave = TWO i's, all 64 j (2 jf), 4 n-granules -> 16 MFMA per kstep
// (512 SIMD-cyc) vs 8 ds_read + ~120 VALU-cyc -> matrix-pipe dominant.
//  - Q (8 rows x 512 k bf16 = 8KB) staged to LDS ONCE; per-kstep Q read is a
//    half-wave-broadcast ds_read_b128. No global loads in the K-loop at all.
//  - A+B double-buffered per 4-kstep phase (8KB + 16KB staged via
//    global_load_lds with a full 2048-cyc phase of slack); 8 barriers total.
//  - Inner loop deliberately simple (no manual reg pipelining — R7 lesson).
//  - Epilogue in-wave per i: max over jf/regs + shfl_xor(32), then
//    relu(S - pos_i.G + c2) (max-trick: relu(Ag-Qg) = max(Ag,Qg) - Qg).
// ---------------------------------------------------------------------------
__launch_bounds__(256, 1)
__global__ void gemm_pool(const __hip_bfloat16* __restrict__ Agb,
                          const __hip_bfloat16* __restrict__ Qgb,
                          const uint4* __restrict__ W2g,
                          const float* __restrict__ pos,
                          const float* __restrict__ G0, const float* __restrict__ G1,
                          const float* __restrict__ c2, float* __restrict__ out) {
  __shared__ uint4 SH[3584];  // A dbuf [0,1024) | B dbuf [1024,3072) | Q [3072,3584)

  int rt = blockIdx.x;   // 0..255: f = rt>>3, i-octet = rt&7
  int ct = blockIdx.y;   // 0..7   d-128 tile
  int f = rt >> 3, i0 = (rt & 7) * 8;

  int t = threadIdx.x, lane = t & 63, w = t >> 6;

  const uint4* aGL = (const uint4*)(Agb + (size_t)f * Pn * Mn) +
                     (size_t)(lane & 31) * 64 + (lane >> 5);
  const uint4* bGL = W2g + (size_t)(4 * ct) * 32 * 64 + lane;

  // stage phase p: A (8 slots of 1KB: ksl*2+jf) + B (16 slots: ksl*4+nf)
  auto stageAB = [&](int p) {
    int buf = p & 1;
#pragma unroll
    for (int s2 = 0; s2 < 2; ++s2) {
      int s = w * 2 + s2;              // 0..7
      int ksl = s >> 1, jf = s & 1;
      dma16(aGL + (size_t)jf * 2048 + (p * 4 + ksl) * 2, SH + buf * 512 + s * 64);
    }
#pragma unroll
    for (int s4 = 0; s4 < 4; ++s4) {
      int sb = w * 4 + s4;             // 0..15
      int ksl = sb >> 2, nf = sb & 3;
      dma16(bGL + (nf * 32 + p * 4 + ksl) * 64, SH + 1024 + buf * 1024 + sb * 64);
    }
  };

  // prologue: Q rows 2w, 2w+1 (once) + phase 0 A/B
  dma16((const uint4*)(Qgb + (size_t)(f * Pn + i0 + 2 * w) * Mn) + lane,
        SH + 3072 + (2 * w) * 64);
  dma16((const uint4*)(Qgb + (size_t)(f * Pn + i0 + 2 * w + 1) * Mn) + lane,
        SH + 3072 + (2 * w + 1) * 64);
  stageAB(0);

  f32x16 acc[2][2][4];  // [ii][jf][nf]
#pragma unroll
  for (int ii = 0; ii < 2; ++ii)
#pragma unroll
    for (int jf = 0; jf < 2; ++jf)
#pragma unroll
      for (int nf = 0; nf < 4; ++nf)
        acc[ii][jf][nf] = (f32x16){0.f,0.f,0.f,0.f,0.f,0.f,0.f,0.f,
                                   0.f,0.f,0.f,0.f,0.f,0.f,0.f,0.f};

  int qbA = 3072 + (2 * w) * 64 + (lane >> 5);
  int qbB = qbA + 64;

#pragma unroll 1
  for (int p = 0; p < 8; ++p) {
    __syncthreads();                // buffer p ready (staged a full phase ago)
    if (p < 7) stageAB(p + 1);      // DMA overlaps this phase's compute
    int ab = (p & 1) * 512 + lane;
    int bb = 1024 + (p & 1) * 1024 + lane;

#pragma unroll 2
    for (int ksl = 0; ksl < 4; ++ksl) {
      int ks = p * 4 + ksl;
      uint4 a0 = SH[ab + (ksl * 2 + 0) * 64];
      uint4 a1 = SH[ab + (ksl * 2 + 1) * 64];
      uint4 qA = SH[qbA + ks * 2];
      uint4 qB = SH[qbB + ks * 2];
      bf16x8 afA0, afA1, afB0, afB1;
      mk2(a0, a1, qA, afA0, afA1);
      mk2(a0, a1, qB, afB0, afB1);
#pragma unroll
      for (int nf = 0; nf < 4; ++nf) {
        bf16x8 bg = __builtin_bit_cast(bf16x8, SH[bb + (ksl * 4 + nf) * 64]);
        acc[0][0][nf] = __builtin_amdgcn_mfma_f32_32x32x16_bf16(afA0, bg, acc[0][0][nf], 0, 0, 0);
        acc[0][1][nf] = __builtin_amdgcn_mfma_f32_32x32x16_bf16(afA1, bg, acc[0][1][nf], 0, 0, 0);
        acc[1][0][nf] = __builtin_amdgcn_mfma_f32_32x32x16_bf16(afB0, bg, acc[1][0][nf], 0, 0, 0);
        acc[1][1][nf] = __builtin_amdgcn_mfma_f32_32x32x16_bf16(afB1, bg, acc[1][1][nf], 0, 0, 0);
      }
    }
  }

  // ---- epilogue (in-wave): max over 64 j, then relu(S - R + c2) ----
  // C layout (32x32): col=lane&31, row=(reg&3)+8*(reg>>2)+4*(lane>>5).
#pragma unroll
  for (int ii = 0; ii < 2; ++ii) {
    int i = i0 + 2 * w + ii;
    float px = pos[(f * Pn + i) * 2], py = pos[(f * Pn + i) * 2 + 1];
#pragma unroll
    for (int nf = 0; nf < 4; ++nf) {
      float mx = -3.0e38f;
#pragma unroll
      for (int jf = 0; jf < 2; ++jf)
#pragma unroll
        for (int rg = 0; rg < 16; ++rg)
          mx = fmaxf(mx, acc[ii][jf][nf][rg]);
      mx = fmaxf(mx, __shfl_xor(mx, 32));
      if (lane < 32) {
        int d = ct * 128 + nf * 32 + (lane & 31);
        float r = px * G0[d] + py * G1[d];
        out[(f * Pn + i) * Dn + d] = fmaxf(mx - r + c2[d], 0.f);
      }
    }
  }
}

// ---------------------------------------------------------------------------
extern "C" void kernel_launch(void* const* d_in, const int* in_sizes, int n_in,
                              void* d_out, int out_size, void* d_ws, size_t ws_size,
                              hipStream_t stream) {
  const float* hs    = (const float*)d_in[0];
  const float* pos   = (const float*)d_in[1];
  // d_in[2] seq_start_end: unused (equal-size frames, P=64)
  const float* We    = (const float*)d_in[3];
  const float* be    = (const float*)d_in[4];
  const float* W1    = (const float*)d_in[5];
  const float* b1    = (const float*)d_in[6];
  const float* g1    = (const float*)d_in[7];
  const float* beta1 = (const float*)d_in[8];
  const float* W2    = (const float*)d_in[9];
  const float* b2    = (const float*)d_in[10];
  const float* g2    = (const float*)d_in[11];
  const float* beta2 = (const float*)d_in[12];
  const float* rm1   = (const float*)d_in[13];
  const float* rv1   = (const float*)d_in[14];
  const float* rm2   = (const float*)d_in[15];
  const float* rv2   = (const float*)d_in[16];

  char* ws = (char*)d_ws;
  // layout: c2 4KB | G0 4KB | G1 4KB | Agb 2MB | Qgb 2MB | W2g 1MB
  float* c2 = (float*)(ws + 0);
  float* G0 = (float*)(ws + 4096);
  float* G1 = (float*)(ws + 8192);
  __hip_bfloat16* Agb = (__hip_bfloat16*)(ws + 12288);
  __hip_bfloat16* Qgb = (__hip_bfloat16*)(ws + 12288 + 2097152);
  uint4* W2g = (uint4*)(ws + 12288 + 2 * 2097152);
  float* out = (float*)d_out;

  prep_all<<<272, 512, 0, stream>>>(hs, pos, We, be, W1, b1, g1, beta1, rm1, rv1,
                                    W2, b2, g2, beta2, rm2, rv2, Agb, Qgb, W2g,
                                    G0, G1, c2);
  gemm_pool<<<dim3(256, 8), 256, 0, stream>>>(Agb, Qgb, W2g, pos, G0, G1, c2, out);
}

// Round 9
// 246.351 us; speedup vs baseline: 1.2176x; 1.0743x over previous
//
#include <hip/hip_runtime.h>
#include <hip/hip_bf16.h>
#include <stdint.h>

#define EPS_BN 1e-5f

constexpr int Fn = 32;    // frames
constexpr int Pn = 64;    // peds per frame
constexpr int Bn = 2048;  // batch
constexpr int Hn = 128;   // h_dim
constexpr int En = 64;    // embed dim
constexpr int Mn = 512;   // GEMM K
constexpr int Dn = 1024;  // GEMM N

using bf16x8  = __attribute__((ext_vector_type(8))) short;
using f32x16  = __attribute__((ext_vector_type(16))) float;

static __device__ __forceinline__ float    bcf(uint32_t u) { return __builtin_bit_cast(float, u); }
static __device__ __forceinline__ uint32_t bcu(float f)    { return __builtin_bit_cast(uint32_t, f); }
static __device__ __forceinline__ unsigned short bfbits(float f) {
  return __builtin_bit_cast(unsigned short, __float2bfloat16(f));
}

// async 16B/lane global -> LDS (LDS base wave-uniform; HW adds lane*16)
static __device__ __forceinline__ void dma16(const uint4* g, const uint4* l) {
  __builtin_amdgcn_global_load_lds(
      (const __attribute__((address_space(1))) unsigned int*)g,
      (__attribute__((address_space(3))) unsigned int*)l, 16, 0, 0);
}

// r0/r1 = bf16 max(a0,q), max(a1,q): packed-pair max with shared q-shift.
// (hi halves compared as fp32 with garbage low mantissa: picks same top16)
static __device__ __forceinline__ void mk2(uint4 a0, uint4 a1, uint4 q,
                                           bf16x8& r0, bf16x8& r1) {
  uint4 x0, x1;
#pragma unroll
  for (int v = 0; v < 4; ++v) {
    uint32_t qw  = ((const uint32_t*)&q)[v];
    uint32_t a0w = ((const uint32_t*)&a0)[v], a1w = ((const uint32_t*)&a1)[v];
    float qlo = bcf(qw << 16);
    float m0lo = fmaxf(bcf(a0w << 16), qlo);
    float m1lo = fmaxf(bcf(a1w << 16), qlo);
    float m0hi = fmaxf(bcf(a0w), bcf(qw));
    float m1hi = fmaxf(bcf(a1w), bcf(qw));
    ((uint32_t*)&x0)[v] = __builtin_amdgcn_perm(bcu(m0hi), bcu(m0lo), 0x07060302u);
    ((uint32_t*)&x1)[v] = __builtin_amdgcn_perm(bcu(m1hi), bcu(m1lo), 0x07060302u);
  }
  r0 = __builtin_bit_cast(bf16x8, x0);
  r1 = __builtin_bit_cast(bf16x8, x1);
}

// ---------------------------------------------------------------------------
// prep_all: 272 blocks x 512 threads (unchanged from R8).
//  [0,128):   Agb/Qgb bf16 (16 batch rows/block), BN1+embedding folded.
//  [128,256): W2g in 32x32x16 MFMA B-fragment granule order (s2 folded).
//  [256,272): G0/G1 (= (Wr .* s1) @ W2s, 2x1024, 64 d-cols/block) + c2.
// ---------------------------------------------------------------------------
__global__ void prep_all(const float* __restrict__ hs, const float* __restrict__ pos,
                         const float* __restrict__ We, const float* __restrict__ be,
                         const float* __restrict__ W1, const float* __restrict__ b1,
                         const float* __restrict__ g1, const float* __restrict__ beta1,
                         const float* __restrict__ rm1, const float* __restrict__ rv1,
                         const float* __restrict__ W2, const float* __restrict__ b2,
                         const float* __restrict__ g2, const float* __restrict__ beta2,
                         const float* __restrict__ rm2, const float* __restrict__ rv2,
                         __hip_bfloat16* __restrict__ Agb, __hip_bfloat16* __restrict__ Qgb,
                         uint4* __restrict__ W2g, float* __restrict__ G0,
                         float* __restrict__ G1, float* __restrict__ c2) {
  __shared__ float smem[64 * 65];
  int bid = blockIdx.x, t = threadIdx.x;
  if (bid < 128) {
    // ---- Ag/Qg for 16 batch rows ----
    int rb = bid * 16, m = t;
    float* hsh = smem;          // 2048 floats
    float* psh = smem + 2048;   // 32 floats
#pragma unroll
    for (int r4 = 0; r4 < 4; ++r4) hsh[r4 * 512 + t] = hs[rb * Hn + r4 * 512 + t];
    if (t < 32) psh[t] = pos[rb * 2 + t];
    __syncthreads();
    float w0 = 0.f, w1 = 0.f, c = 0.f;
    for (int e = 0; e < En; ++e) {
      float w = W1[e * Mn + m];
      w0 += We[e] * w; w1 += We[En + e] * w; c += be[e] * w;
    }
    c += b1[m];
    float s  = g1[m] * rsqrtf(rv1[m] + EPS_BN);
    float tt = beta1[m] - rm1[m] * s;
    float acc[16];
#pragma unroll
    for (int ri = 0; ri < 16; ++ri) acc[ri] = c;
    for (int e = 0; e < Hn; ++e) {
      float w = W1[(En + e) * Mn + m];
#pragma unroll
      for (int ri = 0; ri < 16; ++ri) acc[ri] += hsh[ri * Hn + e] * w;
    }
#pragma unroll
    for (int ri = 0; ri < 16; ++ri) {
      float q = psh[ri * 2] * w0 + psh[ri * 2 + 1] * w1;
      Agb[(rb + ri) * Mn + m] = __float2bfloat16((acc[ri] + q) * s + tt);
      Qgb[(rb + ri) * Mn + m] = __float2bfloat16(q * s);
    }
  } else if (bid < 256) {
    // ---- W2 -> 32-col B-fragment granules (s2 folded) ----
    int b2i = bid - 128;                 // 0..127
    int d0 = (b2i & 15) * 64, k0 = (b2i >> 4) * 64;
    int col = t & 63, row8 = t >> 6;
#pragma unroll
    for (int rr = 0; rr < 8; ++rr) {
      int row = rr * 8 + row8;
      smem[row * 65 + col] = W2[(k0 + row) * Dn + d0 + col];  // [k_local][d_local]
    }
    __syncthreads();
    int lane = t & 63, q8 = t >> 6;
    int sel_n = q8 & 1, sel_ks = q8 >> 1;
    int dl = sel_n * 32 + (lane & 31), d = d0 + dl;
    float sf = g2[d] * rsqrtf(rv2[d] + EPS_BN);
    int kb = sel_ks * 16 + (lane >> 5) * 8;
    uint32_t wd[4];
#pragma unroll
    for (int h = 0; h < 4; ++h) {
      uint32_t u0 = bfbits(smem[(kb + 2 * h) * 65 + dl] * sf);
      uint32_t u1 = bfbits(smem[(kb + 2 * h + 1) * 65 + dl] * sf);
      wd[h] = u0 | (u1 << 16);
    }
    int n32 = (d0 >> 5) + sel_n;
    int ks  = (k0 >> 4) + sel_ks;
    W2g[(n32 * 32 + ks) * 64 + lane] = (uint4){wd[0], wd[1], wd[2], wd[3]};
  } else {
    // ---- G slice (64 d-cols) + c2 ----
    int gb = bid - 256;           // 0..15
    int d0g = gb * 64;
    float* wr0 = smem;            // [0,512)
    float* wr1 = smem + 512;      // [512,1024)
    {
      int m = t;
      float w0 = 0.f, w1 = 0.f;
      for (int e = 0; e < En; ++e) {
        float w = W1[e * Mn + m];
        w0 += We[e] * w; w1 += We[En + e] * w;
      }
      float s = g1[m] * rsqrtf(rv1[m] + EPS_BN);
      wr0[m] = w0 * s; wr1[m] = w1 * s;
    }
    __syncthreads();
    int dl = t & 63, part = t >> 6;   // 8 m-parts x 64 d
    float p0 = 0.f, p1 = 0.f;
#pragma unroll 4
    for (int mm = 0; mm < 64; ++mm) {
      int m = part * 64 + mm;
      float wv = W2[m * Dn + d0g + dl];
      p0 += wr0[m] * wv; p1 += wr1[m] * wv;
    }
    float* pr = smem + 1024;
    pr[part * 64 + dl] = p0;
    pr[512 + part * 64 + dl] = p1;
    __syncthreads();
    if (t < 128) {
      int which = t >> 6, dd = d0g + (t & 63);
      float s2v = g2[dd] * rsqrtf(rv2[dd] + EPS_BN);
      float sum = 0.f;
#pragma unroll
      for (int pp = 0; pp < 8; ++pp) sum += pr[which * 512 + pp * 64 + (t & 63)];
      (which ? G1 : G0)[dd] = sum * s2v;
      if (which == 0) c2[dd] = b2[dd] * s2v + beta2[dd] - rm2[dd] * s2v;
    }
  }
}

// ---------------------------------------------------------------------------
// gemm_pool: 32x32x16 MFMA. Block = 4 i x 64 j x 128 d; wave = ONE i, all 64 j
// (2 jf), 4 n-granules -> 8 MFMA/kstep, acc 128 AGPR + ~100 VGPR -> fits the
// 256-reg budget for 2 waves/SIMD (2 blocks/CU, 52KB LDS). The two resident
// blocks' independent barriers stagger, so one wave's reads/construct hide
// under the other's MFMA block.
//  - Q (4 rows x 512 k = 4KB) staged to LDS ONCE; per-kstep Q is a broadcast
//    ds_read_b128. ZERO global loads inside the K-loop (R6's defect fixed).
//  - A+B double-buffered per 4-kstep phase (8KB + 16KB via global_load_lds,
//    issued right after the previous barrier -> full phase of slack).
//  - Inner loop deliberately simple (no manual reg pipelining — R7 lesson).
//  - Epilogue fully in-wave; max-trick: relu(Ag-Qg) = max(Ag,Qg) - Qg with
//    the -Qg@W2s term restored as R[i,d] = pos_i.G in the epilogue.
// ---------------------------------------------------------------------------
__launch_bounds__(256, 2)
__global__ void gemm_pool(const __hip_bfloat16* __restrict__ Agb,
                          const __hip_bfloat16* __restrict__ Qgb,
                          const uint4* __restrict__ W2g,
                          const float* __restrict__ pos,
                          const float* __restrict__ G0, const float* __restrict__ G1,
                          const float* __restrict__ c2, float* __restrict__ out) {
  __shared__ uint4 SH[3328];  // A dbuf [0,1024) | B dbuf [1024,3072) | Q [3072,3328)

  int ct = blockIdx.x;   // 0..7   d-128 tile
  int rt = blockIdx.y;   // 0..511 (frame, i-quad)
  int f = rt >> 4, i0 = (rt & 15) * 4;

  int t = threadIdx.x, lane = t & 63, w = t >> 6;
  int i = i0 + w;                     // this wave's i

  const uint4* aGL = (const uint4*)(Agb + (size_t)f * Pn * Mn) +
                     (size_t)(lane & 31) * 64 + (lane >> 5);
  const uint4* bGL = W2g + (size_t)(4 * ct) * 32 * 64 + lane;

  // stage phase p (K64): A 8 slots (ksl*2+jf), B 16 slots (ksl*4+nf)
  auto stageAB = [&](int p) {
    int buf = p & 1;
    // A: wave w stages ksl=w, both jf
    dma16(aGL + (size_t)0 * 2048 + (p * 4 + w) * 2, SH + buf * 512 + (w * 2 + 0) * 64);
    dma16(aGL + (size_t)1 * 2048 + (p * 4 + w) * 2, SH + buf * 512 + (w * 2 + 1) * 64);
    // B: wave w stages ksl=w, all nf
#pragma unroll
    for (int nf = 0; nf < 4; ++nf)
      dma16(bGL + (nf * 32 + p * 4 + w) * 64,
            SH + 1024 + buf * 1024 + (w * 4 + nf) * 64);
  };

  // prologue: Q row for this wave's i (once) + phase 0 A/B
  dma16((const uint4*)(Qgb + (size_t)(f * Pn + i) * Mn) + lane, SH + 3072 + w * 64);
  stageAB(0);

  f32x16 acc[2][4];  // [jf][nf]
#pragma unroll
  for (int jf = 0; jf < 2; ++jf)
#pragma unroll
    for (int nf = 0; nf < 4; ++nf)
      acc[jf][nf] = (f32x16){0.f,0.f,0.f,0.f,0.f,0.f,0.f,0.f,
                             0.f,0.f,0.f,0.f,0.f,0.f,0.f,0.f};

  int qb = 3072 + w * 64 + (lane >> 5);

#pragma unroll 1
  for (int p = 0; p < 8; ++p) {
    __syncthreads();                // buffer p ready (staged a full phase ago)
    if (p < 7) stageAB(p + 1);      // next phase's DMA overlaps this compute
    int ab = (p & 1) * 512 + lane;
    int bb = 1024 + (p & 1) * 1024 + lane;

#pragma unroll
    for (int ksl = 0; ksl < 4; ++ksl) {
      int ks = p * 4 + ksl;
      uint4 a0 = SH[ab + (ksl * 2 + 0) * 64];
      uint4 a1 = SH[ab + (ksl * 2 + 1) * 64];
      uint4 q  = SH[qb + ks * 2];   // broadcast read (32-way same-address)
      bf16x8 af0, af1;
      mk2(a0, a1, q, af0, af1);
#pragma unroll
      for (int nf = 0; nf < 4; ++nf) {
        bf16x8 bg = __builtin_bit_cast(bf16x8, SH[bb + (ksl * 4 + nf) * 64]);
        acc[0][nf] = __builtin_amdgcn_mfma_f32_32x32x16_bf16(af0, bg, acc[0][nf], 0, 0, 0);
        acc[1][nf] = __builtin_amdgcn_mfma_f32_32x32x16_bf16(af1, bg, acc[1][nf], 0, 0, 0);
      }
    }
  }

  // ---- epilogue (in-wave): max over 64 j, then relu(S - R + c2) ----
  // C layout (32x32): col=lane&31, row=(reg&3)+8*(reg>>2)+4*(lane>>5).
  float px = pos[(f * Pn + i) * 2], py = pos[(f * Pn + i) * 2 + 1];
#pragma unroll
  for (int nf = 0; nf < 4; ++nf) {
    float mx = -3.0e38f;
#pragma unroll
    for (int jf = 0; jf < 2; ++jf)
#pragma unroll
      for (int rg = 0; rg < 16; ++rg)
        mx = fmaxf(mx, acc[jf][nf][rg]);
    mx = fmaxf(mx, __shfl_xor(mx, 32));
    if (lane < 32) {
      int d = ct * 128 + nf * 32 + (lane & 31);
      float r = px * G0[d] + py * G1[d];
      out[(f * Pn + i) * Dn + d] = fmaxf(mx - r + c2[d], 0.f);
    }
  }
}

// ---------------------------------------------------------------------------
extern "C" void kernel_launch(void* const* d_in, const int* in_sizes, int n_in,
                              void* d_out, int out_size, void* d_ws, size_t ws_size,
                              hipStream_t stream) {
  const float* hs    = (const float*)d_in[0];
  const float* pos   = (const float*)d_in[1];
  // d_in[2] seq_start_end: unused (equal-size frames, P=64)
  const float* We    = (const float*)d_in[3];
  const float* be    = (const float*)d_in[4];
  const float* W1    = (const float*)d_in[5];
  const float* b1    = (const float*)d_in[6];
  const float* g1    = (const float*)d_in[7];
  const float* beta1 = (const float*)d_in[8];
  const float* W2    = (const float*)d_in[9];
  const float* b2    = (const float*)d_in[10];
  const float* g2    = (const float*)d_in[11];
  const float* beta2 = (const float*)d_in[12];
  const float* rm1   = (const float*)d_in[13];
  const float* rv1   = (const float*)d_in[14];
  const float* rm2   = (const float*)d_in[15];
  const float* rv2   = (const float*)d_in[16];

  char* ws = (char*)d_ws;
  // layout: c2 4KB | G0 4KB | G1 4KB | Agb 2MB | Qgb 2MB | W2g 1MB
  float* c2 = (float*)(ws + 0);
  float* G0 = (float*)(ws + 4096);
  float* G1 = (float*)(ws + 8192);
  __hip_bfloat16* Agb = (__hip_bfloat16*)(ws + 12288);
  __hip_bfloat16* Qgb = (__hip_bfloat16*)(ws + 12288 + 2097152);
  uint4* W2g = (uint4*)(ws + 12288 + 2 * 2097152);
  float* out = (float*)d_out;

  prep_all<<<272, 512, 0, stream>>>(hs, pos, We, be, W1, b1, g1, beta1, rm1, rv1,
                                    W2, b2, g2, beta2, rm2, rv2, Agb, Qgb, W2g,
                                    G0, G1, c2);
  gemm_pool<<<dim3(8, 512), 256, 0, stream>>>(Agb, Qgb, W2g, pos, G0, G1, c2, out);
}

// Round 10
// 236.927 us; speedup vs baseline: 1.2660x; 1.0398x over previous
//
#include <hip/hip_runtime.h>
#include <hip/hip_bf16.h>
#include <stdint.h>

#define EPS_BN 1e-5f

constexpr int Fn = 32;    // frames
constexpr int Pn = 64;    // peds per frame
constexpr int Bn = 2048;  // batch
constexpr int Hn = 128;   // h_dim
constexpr int En = 64;    // embed dim
constexpr int Mn = 512;   // GEMM K
constexpr int Dn = 1024;  // GEMM N

using bf16x8  = __attribute__((ext_vector_type(8))) short;
using f32x16  = __attribute__((ext_vector_type(16))) float;

static __device__ __forceinline__ float    bcf(uint32_t u) { return __builtin_bit_cast(float, u); }
static __device__ __forceinline__ uint32_t bcu(float f)    { return __builtin_bit_cast(uint32_t, f); }
static __device__ __forceinline__ unsigned short bfbits(float f) {
  return __builtin_bit_cast(unsigned short, __float2bfloat16(f));
}

// async 16B/lane global -> LDS (LDS base wave-uniform; HW adds lane*16)
static __device__ __forceinline__ void dma16(const uint4* g, const uint4* l) {
  __builtin_amdgcn_global_load_lds(
      (const __attribute__((address_space(1))) unsigned int*)g,
      (__attribute__((address_space(3))) unsigned int*)l, 16, 0, 0);
}

// r0/r1 = bf16 max(a0,q), max(a1,q): packed-pair max with shared q-shift.
// (hi halves compared as fp32 with garbage low mantissa: picks same top16)
static __device__ __forceinline__ void mk2(uint4 a0, uint4 a1, uint4 q,
                                           bf16x8& r0, bf16x8& r1) {
  uint4 x0, x1;
#pragma unroll
  for (int v = 0; v < 4; ++v) {
    uint32_t qw  = ((const uint32_t*)&q)[v];
    uint32_t a0w = ((const uint32_t*)&a0)[v], a1w = ((const uint32_t*)&a1)[v];
    float qlo = bcf(qw << 16);
    float m0lo = fmaxf(bcf(a0w << 16), qlo);
    float m1lo = fmaxf(bcf(a1w << 16), qlo);
    float m0hi = fmaxf(bcf(a0w), bcf(qw));
    float m1hi = fmaxf(bcf(a1w), bcf(qw));
    ((uint32_t*)&x0)[v] = __builtin_amdgcn_perm(bcu(m0hi), bcu(m0lo), 0x07060302u);
    ((uint32_t*)&x1)[v] = __builtin_amdgcn_perm(bcu(m1hi), bcu(m1lo), 0x07060302u);
  }
  r0 = __builtin_bit_cast(bf16x8, x0);
  r1 = __builtin_bit_cast(bf16x8, x1);
}

// ---------------------------------------------------------------------------
// prep_all: 400 blocks x 512 threads.
//  [0,256):   Agb/Qgb bf16 (8 batch rows/block). h/pos read via WAVE-UNIFORM
//             global loads -> compiler scalarizes to s_load + v_fmac(v,s,v):
//             no LDS broadcast reads (the 40+ us tax of R7-R9's prep).
//  [256,384): W2g in 32x32x16 MFMA B-fragment granule order (s2 folded).
//  [384,400): G0/G1 (= (Wr .* s1) @ W2s, 2x1024, 64 d-cols/block) + c2.
// ---------------------------------------------------------------------------
__global__ void prep_all(const float* __restrict__ hs, const float* __restrict__ pos,
                         const float* __restrict__ We, const float* __restrict__ be,
                         const float* __restrict__ W1, const float* __restrict__ b1,
                         const float* __restrict__ g1, const float* __restrict__ beta1,
                         const float* __restrict__ rm1, const float* __restrict__ rv1,
                         const float* __restrict__ W2, const float* __restrict__ b2,
                         const float* __restrict__ g2, const float* __restrict__ beta2,
                         const float* __restrict__ rm2, const float* __restrict__ rv2,
                         __hip_bfloat16* __restrict__ Agb, __hip_bfloat16* __restrict__ Qgb,
                         uint4* __restrict__ W2g, float* __restrict__ G0,
                         float* __restrict__ G1, float* __restrict__ c2) {
  __shared__ float smem[64 * 65];
  int bid = blockIdx.x, t = threadIdx.x;
  if (bid < 256) {
    // ---- Ag/Qg for 8 batch rows, no LDS ----
    int rb = bid * 8, m = t;
    float w0 = 0.f, w1 = 0.f, c = 0.f;
    for (int e = 0; e < En; ++e) {
      float w = W1[e * Mn + m];
      w0 += We[e] * w; w1 += We[En + e] * w; c += be[e] * w;
    }
    c += b1[m];
    float s  = g1[m] * rsqrtf(rv1[m] + EPS_BN);
    float tt = beta1[m] - rm1[m] * s;
    float acc[8];
#pragma unroll
    for (int ri = 0; ri < 8; ++ri) acc[ri] = c;
#pragma unroll 4
    for (int e = 0; e < Hn; ++e) {
      float w = W1[(En + e) * Mn + m];
#pragma unroll
      for (int ri = 0; ri < 8; ++ri)
        acc[ri] += hs[(rb + ri) * Hn + e] * w;   // uniform addr -> s_load
    }
#pragma unroll
    for (int ri = 0; ri < 8; ++ri) {
      float q = pos[(rb + ri) * 2] * w0 + pos[(rb + ri) * 2 + 1] * w1;  // uniform
      Agb[(rb + ri) * Mn + m] = __float2bfloat16((acc[ri] + q) * s + tt);
      Qgb[(rb + ri) * Mn + m] = __float2bfloat16(q * s);
    }
  } else if (bid < 384) {
    // ---- W2 -> 32-col B-fragment granules (s2 folded) ----
    int b2i = bid - 256;                 // 0..127
    int d0 = (b2i & 15) * 64, k0 = (b2i >> 4) * 64;
    int col = t & 63, row8 = t >> 6;
#pragma unroll
    for (int rr = 0; rr < 8; ++rr) {
      int row = rr * 8 + row8;
      smem[row * 65 + col] = W2[(k0 + row) * Dn + d0 + col];  // [k_local][d_local]
    }
    __syncthreads();
    int lane = t & 63, q8 = t >> 6;
    int sel_n = q8 & 1, sel_ks = q8 >> 1;
    int dl = sel_n * 32 + (lane & 31), d = d0 + dl;
    float sf = g2[d] * rsqrtf(rv2[d] + EPS_BN);
    int kb = sel_ks * 16 + (lane >> 5) * 8;
    uint32_t wd[4];
#pragma unroll
    for (int h = 0; h < 4; ++h) {
      uint32_t u0 = bfbits(smem[(kb + 2 * h) * 65 + dl] * sf);
      uint32_t u1 = bfbits(smem[(kb + 2 * h + 1) * 65 + dl] * sf);
      wd[h] = u0 | (u1 << 16);
    }
    int n32 = (d0 >> 5) + sel_n;
    int ks  = (k0 >> 4) + sel_ks;
    W2g[(n32 * 32 + ks) * 64 + lane] = (uint4){wd[0], wd[1], wd[2], wd[3]};
  } else {
    // ---- G slice (64 d-cols) + c2 ----
    int gb = bid - 384;           // 0..15
    int d0g = gb * 64;
    float* wr0 = smem;            // [0,512)
    float* wr1 = smem + 512;      // [512,1024)
    {
      int m = t;
      float w0 = 0.f, w1 = 0.f;
      for (int e = 0; e < En; ++e) {
        float w = W1[e * Mn + m];
        w0 += We[e] * w; w1 += We[En + e] * w;
      }
      float s = g1[m] * rsqrtf(rv1[m] + EPS_BN);
      wr0[m] = w0 * s; wr1[m] = w1 * s;
    }
    __syncthreads();
    int dl = t & 63, part = t >> 6;   // 8 m-parts x 64 d
    float p0 = 0.f, p1 = 0.f;
#pragma unroll 4
    for (int mm = 0; mm < 64; ++mm) {
      int m = part * 64 + mm;
      float wv = W2[m * Dn + d0g + dl];
      p0 += wr0[m] * wv; p1 += wr1[m] * wv;
    }
    float* pr = smem + 1024;
    pr[part * 64 + dl] = p0;
    pr[512 + part * 64 + dl] = p1;
    __syncthreads();
    if (t < 128) {
      int which = t >> 6, dd = d0g + (t & 63);
      float s2v = g2[dd] * rsqrtf(rv2[dd] + EPS_BN);
      float sum = 0.f;
#pragma unroll
      for (int pp = 0; pp < 8; ++pp) sum += pr[which * 512 + pp * 64 + (t & 63)];
      (which ? G1 : G0)[dd] = sum * s2v;
      if (which == 0) c2[dd] = b2[dd] * s2v + beta2[dd] - rm2[dd] * s2v;
    }
  }
}

// ---------------------------------------------------------------------------
// gemm_pool (UNCHANGED from R9 — 148 us, MfmaUtil 42%, conflicts 0).
// 32x32x16 MFMA. Block = 4 i x 64 j x 128 d; wave = ONE i, all 64 j (2 jf),
// 4 n-granules -> 8 MFMA/kstep, 2 waves/SIMD, 2 blocks/CU, 52KB LDS.
// Q staged to LDS once; A+B double-buffered per K64 phase via global_load_lds;
// zero global loads inside the K-loop; epilogue fully in-wave (max-trick).
// ---------------------------------------------------------------------------
__launch_bounds__(256, 2)
__global__ void gemm_pool(const __hip_bfloat16* __restrict__ Agb,
                          const __hip_bfloat16* __restrict__ Qgb,
                          const uint4* __restrict__ W2g,
                          const float* __restrict__ pos,
                          const float* __restrict__ G0, const float* __restrict__ G1,
                          const float* __restrict__ c2, float* __restrict__ out) {
  __shared__ uint4 SH[3328];  // A dbuf [0,1024) | B dbuf [1024,3072) | Q [3072,3328)

  int ct = blockIdx.x;   // 0..7   d-128 tile
  int rt = blockIdx.y;   // 0..511 (frame, i-quad)
  int f = rt >> 4, i0 = (rt & 15) * 4;

  int t = threadIdx.x, lane = t & 63, w = t >> 6;
  int i = i0 + w;                     // this wave's i

  const uint4* aGL = (const uint4*)(Agb + (size_t)f * Pn * Mn) +
                     (size_t)(lane & 31) * 64 + (lane >> 5);
  const uint4* bGL = W2g + (size_t)(4 * ct) * 32 * 64 + lane;

  // stage phase p (K64): A 8 slots (ksl*2+jf), B 16 slots (ksl*4+nf)
  auto stageAB = [&](int p) {
    int buf = p & 1;
    dma16(aGL + (size_t)0 * 2048 + (p * 4 + w) * 2, SH + buf * 512 + (w * 2 + 0) * 64);
    dma16(aGL + (size_t)1 * 2048 + (p * 4 + w) * 2, SH + buf * 512 + (w * 2 + 1) * 64);
#pragma unroll
    for (int nf = 0; nf < 4; ++nf)
      dma16(bGL + (nf * 32 + p * 4 + w) * 64,
            SH + 1024 + buf * 1024 + (w * 4 + nf) * 64);
  };

  // prologue: Q row for this wave's i (once) + phase 0 A/B
  dma16((const uint4*)(Qgb + (size_t)(f * Pn + i) * Mn) + lane, SH + 3072 + w * 64);
  stageAB(0);

  f32x16 acc[2][4];  // [jf][nf]
#pragma unroll
  for (int jf = 0; jf < 2; ++jf)
#pragma unroll
    for (int nf = 0; nf < 4; ++nf)
      acc[jf][nf] = (f32x16){0.f,0.f,0.f,0.f,0.f,0.f,0.f,0.f,
                             0.f,0.f,0.f,0.f,0.f,0.f,0.f,0.f};

  int qb = 3072 + w * 64 + (lane >> 5);

#pragma unroll 1
  for (int p = 0; p < 8; ++p) {
    __syncthreads();                // buffer p ready (staged a full phase ago)
    if (p < 7) stageAB(p + 1);      // next phase's DMA overlaps this compute
    int ab = (p & 1) * 512 + lane;
    int bb = 1024 + (p & 1) * 1024 + lane;

#pragma unroll
    for (int ksl = 0; ksl < 4; ++ksl) {
      int ks = p * 4 + ksl;
      uint4 a0 = SH[ab + (ksl * 2 + 0) * 64];
      uint4 a1 = SH[ab + (ksl * 2 + 1) * 64];
      uint4 q  = SH[qb + ks * 2];   // broadcast read
      bf16x8 af0, af1;
      mk2(a0, a1, q, af0, af1);
#pragma unroll
      for (int nf = 0; nf < 4; ++nf) {
        bf16x8 bg = __builtin_bit_cast(bf16x8, SH[bb + (ksl * 4 + nf) * 64]);
        acc[0][nf] = __builtin_amdgcn_mfma_f32_32x32x16_bf16(af0, bg, acc[0][nf], 0, 0, 0);
        acc[1][nf] = __builtin_amdgcn_mfma_f32_32x32x16_bf16(af1, bg, acc[1][nf], 0, 0, 0);
      }
    }
  }

  // ---- epilogue (in-wave): max over 64 j, then relu(S - R + c2) ----
  // C layout (32x32): col=lane&31, row=(reg&3)+8*(reg>>2)+4*(lane>>5).
  float px = pos[(f * Pn + i) * 2], py = pos[(f * Pn + i) * 2 + 1];
#pragma unroll
  for (int nf = 0; nf < 4; ++nf) {
    float mx = -3.0e38f;
#pragma unroll
    for (int jf = 0; jf < 2; ++jf)
#pragma unroll
      for (int rg = 0; rg < 16; ++rg)
        mx = fmaxf(mx, acc[jf][nf][rg]);
    mx = fmaxf(mx, __shfl_xor(mx, 32));
    if (lane < 32) {
      int d = ct * 128 + nf * 32 + (lane & 31);
      float r = px * G0[d] + py * G1[d];
      out[(f * Pn + i) * Dn + d] = fmaxf(mx - r + c2[d], 0.f);
    }
  }
}

// ---------------------------------------------------------------------------
extern "C" void kernel_launch(void* const* d_in, const int* in_sizes, int n_in,
                              void* d_out, int out_size, void* d_ws, size_t ws_size,
                              hipStream_t stream) {
  const float* hs    = (const float*)d_in[0];
  const float* pos   = (const float*)d_in[1];
  // d_in[2] seq_start_end: unused (equal-size frames, P=64)
  const float* We    = (const float*)d_in[3];
  const float* be    = (const float*)d_in[4];
  const float* W1    = (const float*)d_in[5];
  const float* b1    = (const float*)d_in[6];
  const float* g1    = (const float*)d_in[7];
  const float* beta1 = (const float*)d_in[8];
  const float* W2    = (const float*)d_in[9];
  const float* b2    = (const float*)d_in[10];
  const float* g2    = (const float*)d_in[11];
  const float* beta2 = (const float*)d_in[12];
  const float* rm1   = (const float*)d_in[13];
  const float* rv1   = (const float*)d_in[14];
  const float* rm2   = (const float*)d_in[15];
  const float* rv2   = (const float*)d_in[16];

  char* ws = (char*)d_ws;
  // layout: c2 4KB | G0 4KB | G1 4KB | Agb 2MB | Qgb 2MB | W2g 1MB
  float* c2 = (float*)(ws + 0);
  float* G0 = (float*)(ws + 4096);
  float* G1 = (float*)(ws + 8192);
  __hip_bfloat16* Agb = (__hip_bfloat16*)(ws + 12288);
  __hip_bfloat16* Qgb = (__hip_bfloat16*)(ws + 12288 + 2097152);
  uint4* W2g = (uint4*)(ws + 12288 + 2 * 2097152);
  float* out = (float*)d_out;

  prep_all<<<400, 512, 0, stream>>>(hs, pos, We, be, W1, b1, g1, beta1, rm1, rv1,
                                    W2, b2, g2, beta2, rm2, rv2, Agb, Qgb, W2g,
                                    G0, G1, c2);
  gemm_pool<<<dim3(8, 512), 256, 0, stream>>>(Agb, Qgb, W2g, pos, G0, G1, c2, out);
}